// Round 5
// baseline (271.858 us; speedup 1.0000x reference)
//
#include <hip/hip_runtime.h>
#include <hip/hip_bf16.h>
#include <math.h>

// Problem constants (fixed by setup_inputs)
#define N_NODES 1024
#define F_DIM   1024
#define H_DIM   512
#define E_EDGES 32768
#define B_GRAPHS 16
#define OUT_DIM 10
#define FH_DIM  1536
#define EPS 1e-5f
#define MH_C_F 0.8673250705840776f
#define INV_SQRT2 0.70710678118654752440f

#if __has_builtin(__builtin_amdgcn_exp2f)
#define EXP2F(x) __builtin_amdgcn_exp2f(x)
#else
#define EXP2F(x) exp2f(x)
#endif
#define CEXP (-0.72134752044448170368f)   // -0.5 * log2(e);  e^{-x2/2} = 2^{CEXP*x2}
#define WM_C (MH_C_F / 0.72134752044448170368f)  // so wm*arg = -MH_C*x2

// ---------------- K1 k_pre: h / param-pack / x-stats / out-bias-init ----------------
// blocks [0,1024): h (float4); [1024,2048): pack; [2048,2064): x col-stat partials;
// block 2064: d_out init with fc2 bias.
__global__ __launch_bounds__(256) void k_pre(const float* __restrict__ x,
                                             const float* __restrict__ watt,
                                             const float* __restrict__ scale,
                                             const float* __restrict__ trans,
                                             const float* __restrict__ ww,
                                             const float* __restrict__ bw,
                                             const float* __restrict__ fc2_b,
                                             float* __restrict__ h,
                                             float4* __restrict__ pkA,
                                             float2* __restrict__ pkB,
                                             float* __restrict__ xpart,
                                             float* __restrict__ xpart2,
                                             float* __restrict__ outp) {
    const int b = blockIdx.x;
    const int t = threadIdx.x;
    if (b < 1024) {
        int idx = b * 256 + t;                 // over N*F/4
        float4 p = ((const float4*)x)[idx];
        float w0 = watt[0], w1 = watt[1];
        float lo0 = (p.x + p.y) * INV_SQRT2, hi0 = (p.x - p.y) * INV_SQRT2;
        float lo1 = (p.z + p.w) * INV_SQRT2, hi1 = (p.z - p.w) * INV_SQRT2;
        float t0 = lo0 * w0 + hi0 * w1;
        float t1 = lo1 * w0 + hi1 * w1;
        float s0 = 1.0f / (1.0f + __expf(-t0));
        float s1 = 1.0f / (1.0f + __expf(-t1));
        float2 o2;
        o2.x = s0 * lo0 + (1.0f - s0) * hi0;
        o2.y = s1 * lo1 + (1.0f - s1) * hi1;
        ((float2*)h)[idx] = o2;
    } else if (b < 2048) {
        int g = (b - 1024) * 256 + t;          // 0 .. H*H-1  ([o][i])
        float iv = 1.0f / scale[g];
        float f  = trans[g] * iv;
        float wv = ww[g];
        float4 pa;
        pa.x = CEXP * iv * iv;                 // c1
        pa.y = -2.0f * CEXP * iv * f;          // c2
        pa.z = CEXP * f * f;                   // c3
        pa.w = MH_C_F * wv;                    // w'
        pkA[g] = pa;
        float2 pb;
        pb.x = WM_C * wv;                      // wm'  (wm'*arg = -MH_C*wv*x2)
        pb.y = bw[g];
        pkB[g] = pb;
    } else if (b < 2064) {
        int gr = b - 2048;                     // 64-row group
        float s[4] = {}, s2[4] = {};
        for (int r = 0; r < 64; ++r) {
            int row = gr * 64 + r;
            #pragma unroll
            for (int ch = 0; ch < 4; ++ch) {
                float v = x[row * F_DIM + ch * 256 + t];
                s[ch] += v; s2[ch] += v * v;
            }
        }
        #pragma unroll
        for (int ch = 0; ch < 4; ++ch) {
            xpart [gr * F_DIM + ch * 256 + t] = s[ch];
            xpart2[gr * F_DIM + ch * 256 + t] = s2[ch];
        }
    } else {
        if (t < B_GRAPHS * OUT_DIM) outp[t] = fc2_b[t % OUT_DIM];
    }
}

// ---------------- K2 k_edge: hist + scan + cursors + graph ranges (1 block) ----------------
__global__ __launch_bounds__(1024) void k_edge(const int* __restrict__ dst,
                                               const int* __restrict__ batch,
                                               int* __restrict__ deg,
                                               int* __restrict__ start,
                                               int* __restrict__ cursor,
                                               int* __restrict__ gstart,
                                               int* __restrict__ gcnt) {
    __shared__ int sh[N_NODES];
    __shared__ int cs[B_GRAPHS], ss[B_GRAPHS];
    const int t = threadIdx.x;
    sh[t] = 0;
    if (t < B_GRAPHS) { cs[t] = 0; ss[t] = 0; }
    __syncthreads();
    for (int e = t; e < E_EDGES; e += 1024) atomicAdd(&sh[dst[e]], 1);
    __syncthreads();
    int d0 = sh[t];
    __syncthreads();
    for (int off = 1; off < N_NODES; off <<= 1) {
        int v = (t >= off) ? sh[t - off] : 0;
        __syncthreads();
        sh[t] += v;
        __syncthreads();
    }
    int excl = sh[t] - d0;
    deg[t] = d0; start[t] = excl; cursor[t] = excl;
    // graph ranges (batch sorted)
    int bb = batch[t];
    atomicAdd(&cs[bb], 1);
    if (t == 0 || batch[t - 1] != bb) ss[bb] = t;
    __syncthreads();
    if (t < B_GRAPHS) { gstart[t] = ss[t]; gcnt[t] = cs[t]; }
}

// ---------------- K3 k_fill: bucket edges by dst ----------------
__global__ __launch_bounds__(256) void k_fill(const int* __restrict__ src,
                                              const int* __restrict__ dst,
                                              int* __restrict__ cursor,
                                              int* __restrict__ elist) {
    int e = blockIdx.x * 256 + threadIdx.x;
    int slot = atomicAdd(&cursor[dst[e]], 1);
    elist[slot] = src[e];
}

// ---------------- K4 k_gather: agg[d] = h[d] + sum h[src] (atomic-free) ----------------
__global__ __launch_bounds__(256) void k_gather(const float* __restrict__ h,
                                                const int* __restrict__ start,
                                                const int* __restrict__ deg,
                                                const int* __restrict__ elist,
                                                float* __restrict__ agg) {
    __shared__ int se[256];
    const int d = blockIdx.x;
    const int t = threadIdx.x;
    const int st = start[d], dg = deg[d];
    float a0 = h[d * H_DIM + t];
    float a1 = h[d * H_DIM + t + 256];
    for (int base = 0; base < dg; base += 256) {
        int m = dg - base; if (m > 256) m = 256;
        __syncthreads();
        if (t < m) se[t] = elist[st + base + t];
        __syncthreads();
        for (int k = 0; k < m; ++k) {
            int s = se[k];
            a0 += h[s * H_DIM + t];
            a1 += h[s * H_DIM + t + 256];
        }
    }
    agg[d * H_DIM + t]       = a0;
    agg[d * H_DIM + t + 256] = a1;
}

// ---------------- K5 k_wavelet: vbp[z][n][o] partials, 6 VALU + 1 exp per pair ----------------
#define TN 64
#define TO 32
#define KI 8
#define ZSPLIT 8
#define ZLEN (H_DIM / ZSPLIT)   // 64
#define SA_STR 68               // floats; 17 float4s — conflict-free stage writes
#define SP_STR 33               // float4/float2 units — conflict-free stage writes
__global__ __launch_bounds__(256, 8) void k_wavelet(const float* __restrict__ agg,
                                                    const float4* __restrict__ pkA,
                                                    const float2* __restrict__ pkB,
                                                    float* __restrict__ vbp) {
    __shared__ float sA[KI * SA_STR];
    __shared__ float sL[KI * SA_STR];
    __shared__ float4 sPA[KI * SP_STR];
    __shared__ float2 sPB[KI * SP_STR];

    const int t  = threadIdx.x;
    const int n0 = blockIdx.x * TN;
    const int o0 = blockIdx.y * TO;
    const int z0 = blockIdx.z * ZLEN;
    const int og = t & 15;       // o = o0 + og + 16*j
    const int n4 = t >> 4;       // n-quad: n = n0 + n4*4 + nn

    float accw[2][4] = {};
    float accb[2][4] = {};

    for (int stg = 0; stg < ZLEN / KI; ++stg) {
        const int i0 = z0 + stg * KI;
        __syncthreads();
        if (t < 128) {           // A-tile: 64 n x 8 i, transposed into [ii][n], + silu
            int n = t >> 1, c = t & 1;
            float4 a = *(const float4*)&agg[(n0 + n) * H_DIM + i0 + c * 4];
            float av[4] = {a.x, a.y, a.z, a.w};
            #pragma unroll
            for (int k = 0; k < 4; ++k) {
                int ii = c * 4 + k;
                sA[ii * SA_STR + n] = av[k];
                sL[ii * SA_STR + n] = av[k] / (1.0f + __expf(-av[k]));
            }
        }
        {                        // params: 32 o x 8 i
            int o = t >> 3, ii = t & 7;
            int g = (o0 + o) * H_DIM + i0 + ii;
            sPA[ii * SP_STR + o] = pkA[g];
            sPB[ii * SP_STR + o] = pkB[g];
        }
        __syncthreads();
        #pragma unroll
        for (int ii = 0; ii < KI; ++ii) {
            float4 a4 = ((const float4*)sA)[ii * (SA_STR / 4) + n4];
            float4 l4 = ((const float4*)sL)[ii * (SA_STR / 4) + n4];
            float av[4] = {a4.x, a4.y, a4.z, a4.w};
            float lv[4] = {l4.x, l4.y, l4.z, l4.w};
            float a2[4] = {av[0]*av[0], av[1]*av[1], av[2]*av[2], av[3]*av[3]};
            #pragma unroll
            for (int j = 0; j < 2; ++j) {
                float4 pa = sPA[ii * SP_STR + og + 16 * j];
                float2 pb = sPB[ii * SP_STR + og + 16 * j];
                #pragma unroll
                for (int nn = 0; nn < 4; ++nn) {
                    float arg = fmaf(a2[nn], pa.x, fmaf(av[nn], pa.y, pa.z));
                    float e   = EXP2F(arg);
                    float te  = arg * e;
                    accw[j][nn] = fmaf(e, pa.w, fmaf(te, pb.x, accw[j][nn]));
                    accb[j][nn] = fmaf(lv[nn], pb.y, accb[j][nn]);
                }
            }
        }
    }
    float* outz = vbp + (size_t)blockIdx.z * (N_NODES * H_DIM);
    #pragma unroll
    for (int nn = 0; nn < 4; ++nn) {
        #pragma unroll
        for (int j = 0; j < 2; ++j) {
            outz[(n0 + n4 * 4 + nn) * H_DIM + o0 + og + 16 * j] =
                accw[j][nn] + accb[j][nn];
        }
    }
}

// ---------------- K6 k_reduce: sum partials -> vb + per-strip column stats ----------------
__global__ __launch_bounds__(256) void k_reduce(const float* __restrict__ vbp,
                                                float* __restrict__ vb,
                                                float* __restrict__ vpart,
                                                float* __restrict__ vpart2) {
    const int b = blockIdx.x;           // 64 blocks: 8 o-strips x 8 n-strips
    const int o0 = (b & 7) * 64;
    const int nstrip = b >> 3;
    const int n0 = nstrip * 128;
    const int t = threadIdx.x;
    const int oc = o0 + (t & 63);
    const int nsub = t >> 6;
    float s = 0.f, s2 = 0.f;
    for (int r = 0; r < 32; ++r) {
        int n = n0 + r * 4 + nsub;
        size_t idx = (size_t)n * H_DIM + oc;
        float v = 0.f;
        #pragma unroll
        for (int z = 0; z < ZSPLIT; ++z) v += vbp[z * (N_NODES * H_DIM) + idx];
        vb[idx] = v;
        s += v; s2 += v * v;
    }
    __shared__ float sh1[256], sh2[256];
    sh1[t] = s; sh2[t] = s2;
    __syncthreads();
    if (t < 64) {
        s  = sh1[t] + sh1[t + 64] + sh1[t + 128] + sh1[t + 192];
        s2 = sh2[t] + sh2[t + 64] + sh2[t + 128] + sh2[t + 192];
        vpart [nstrip * H_DIM + o0 + t] = s;
        vpart2[nstrip * H_DIM + o0 + t] = s2;
    }
}

// ---------------- K7 k_pool: BN-finalize (inline) + segment-mean, grid (6, B) ----------------
__global__ __launch_bounds__(256) void k_pool(const float* __restrict__ x,
                                              const float* __restrict__ vb,
                                              const int* __restrict__ gstart,
                                              const int* __restrict__ gcnt,
                                              const float* __restrict__ xpart,
                                              const float* __restrict__ xpart2,
                                              const float* __restrict__ vpart,
                                              const float* __restrict__ vpart2,
                                              float* __restrict__ pooled) {
    const int b = blockIdx.y;
    const int ch = blockIdx.x;          // 0..5
    const int t = threadIdx.x;
    const int cnt = gcnt[b], st = gstart[b];
    if (ch < 4) {
        int c = ch * 256 + t;           // x column
        float s = 0.f, s2 = 0.f;
        #pragma unroll
        for (int g = 0; g < 16; ++g) { s += xpart[g * F_DIM + c]; s2 += xpart2[g * F_DIM + c]; }
        float mu  = s * (1.0f / N_NODES);
        float var = s2 * (1.0f / N_NODES) - mu * mu;
        if (var < 0.f) var = 0.f;
        float S = 1.0f / sqrtf(var + EPS);
        float acc = 0.f;
        for (int r = 0; r < cnt; ++r) acc += x[(st + r) * F_DIM + c];
        float out = (cnt > 0) ? (acc / (float)cnt - mu) * S : 0.f;
        pooled[b * FH_DIM + c] = out;
    } else {
        int c = (ch - 4) * 256 + t;     // vb column — triple-BN fold
        float s = 0.f, s2 = 0.f;
        #pragma unroll
        for (int g = 0; g < 8; ++g) { s += vpart[g * H_DIM + c]; s2 += vpart2[g * H_DIM + c]; }
        float mu  = s * (1.0f / N_NODES);
        float var = s2 * (1.0f / N_NODES) - mu * mu;
        if (var < 0.f) var = 0.f;
        float s1v = 1.0f / sqrtf(var + EPS);
        float v1  = var * s1v * s1v;
        float s2v = 1.0f / sqrtf(v1 + EPS);
        float v2  = v1 * s2v * s2v;
        float s3v = 1.0f / sqrtf(v2 + EPS);
        float S = s1v * s2v * s3v;
        float acc = 0.f;
        for (int r = 0; r < cnt; ++r) acc += vb[(st + r) * H_DIM + c];
        float out = (cnt > 0) ? (acc / (float)cnt - mu) * S : 0.f;
        pooled[b * FH_DIM + F_DIM + c] = out;
    }
}

// ---------------- K8 k_fc1out: fc1 + relu + fc2 epilogue (atomic into d_out) ----------------
// one wave per fc1-output o; 16 graph accumulators; fc1_w read exactly once.
__global__ __launch_bounds__(256) void k_fc1out(const float* __restrict__ pooled,
                                                const float* __restrict__ w1,
                                                const float* __restrict__ b1,
                                                const float* __restrict__ w2,
                                                float* __restrict__ outp) {
    const int o = blockIdx.x * 4 + (threadIdx.x >> 6);   // 0..511
    const int lane = threadIdx.x & 63;
    float acc[B_GRAPHS] = {};
    const float* wr = w1 + o * FH_DIM;
    for (int k = lane; k < FH_DIM; k += 64) {
        float wv = wr[k];
        #pragma unroll
        for (int b = 0; b < B_GRAPHS; ++b) acc[b] += wv * pooled[b * FH_DIM + k];
    }
    #pragma unroll
    for (int b = 0; b < B_GRAPHS; ++b) {
        #pragma unroll
        for (int off = 32; off > 0; off >>= 1) acc[b] += __shfl_down(acc[b], off);
    }
    float bs = b1[o];
    float wu = (lane < OUT_DIM) ? w2[lane * H_DIM + o] : 0.f;
    #pragma unroll
    for (int b = 0; b < B_GRAPHS; ++b) {
        float r = __shfl(acc[b], 0);
        r = fmaxf(r + bs, 0.f);
        if (lane < OUT_DIM) unsafeAtomicAdd(&outp[b * OUT_DIM + lane], r * wu);
    }
}

extern "C" void kernel_launch(void* const* d_in, const int* in_sizes, int n_in,
                              void* d_out, int out_size, void* d_ws, size_t ws_size,
                              hipStream_t stream) {
    const float* x       = (const float*)d_in[0];
    const float* w_att   = (const float*)d_in[1];
    const float* wk_scale= (const float*)d_in[2];
    const float* wk_trans= (const float*)d_in[3];
    const float* wk_wav  = (const float*)d_in[4];
    const float* wk_base = (const float*)d_in[5];
    const float* fc1_w   = (const float*)d_in[6];
    const float* fc1_b   = (const float*)d_in[7];
    const float* fc2_w   = (const float*)d_in[8];
    const float* fc2_b   = (const float*)d_in[9];
    const int*   eidx    = (const int*)d_in[10];
    const int*   batch   = (const int*)d_in[11];
    float* outp = (float*)d_out;

    float* ws = (float*)d_ws;
    const int NH = N_NODES * H_DIM;            // 524288
    float*  h      = ws;                       // NH
    float*  agg    = h + NH;                   // NH
    float4* pkA    = (float4*)(agg + NH);      // H*H f4
    float2* pkB    = (float2*)((float*)pkA + 4 * H_DIM * H_DIM); // H*H f2
    float*  vbp    = (float*)pkB + 2 * H_DIM * H_DIM;            // 8*NH
    float*  vb     = vbp + (size_t)ZSPLIT * NH;// NH
    float*  vpart  = vb + NH;                  // 8*512
    float*  vpart2 = vpart + 8 * H_DIM;        // 8*512
    float*  xpart  = vpart2 + 8 * H_DIM;       // 16*1024
    float*  xpart2 = xpart + 16 * F_DIM;       // 16*1024
    float*  pooled = xpart2 + 16 * F_DIM;      // 16*1536
    int*    deg    = (int*)(pooled + B_GRAPHS * FH_DIM); // 1024
    int*    estart = deg + N_NODES;
    int*    cursor = estart + N_NODES;
    int*    elist  = cursor + N_NODES;         // 32768
    int*    gstart = elist + E_EDGES;          // 16
    int*    gcnt   = gstart + 16;              // 16

    const int* src = eidx;
    const int* dst = eidx + E_EDGES;

    k_pre<<<2065, 256, 0, stream>>>(x, w_att, wk_scale, wk_trans, wk_wav, wk_base,
                                    fc2_b, h, pkA, pkB, xpart, xpart2, outp);
    k_edge<<<1, 1024, 0, stream>>>(dst, batch, deg, estart, cursor, gstart, gcnt);
    k_fill<<<E_EDGES / 256, 256, 0, stream>>>(src, dst, cursor, elist);
    k_gather<<<N_NODES, 256, 0, stream>>>(h, estart, deg, elist, agg);
    {
        dim3 grid(N_NODES / TN, H_DIM / TO, ZSPLIT);   // 16 x 16 x 8 = 2048
        k_wavelet<<<grid, 256, 0, stream>>>(agg, pkA, pkB, vbp);
    }
    k_reduce<<<64, 256, 0, stream>>>(vbp, vb, vpart, vpart2);
    {
        dim3 grid(6, B_GRAPHS);
        k_pool<<<grid, 256, 0, stream>>>(x, vb, gstart, gcnt,
                                         xpart, xpart2, vpart, vpart2, pooled);
    }
    k_fc1out<<<H_DIM / 4, 256, 0, stream>>>(pooled, fc1_w, fc1_b, fc2_w, outp);
}